// Round 8
// baseline (131.900 us; speedup 1.0000x reference)
//
#include <hip/hip_runtime.h>

// Fused iterated 3x3 median blur (edge-replicate), up to 9 iterations.
// WAVE-SYNCHRONOUS version: block = 64 threads = 1 wave, so __syncthreads()
// is barrier-free (compiler elides s_barrier for single-wave workgroups;
// only a fence + waitcnt remains) and waves are fully decoupled.
// 32x32 output tile + 9 halo = 50x50 LDS (stride 52, 10.4 KB).
// Thread grid 8x8, each thread owns a contiguous 6x6 patch of compute
// region [1,48]^2 (2304 = 64*36) kept in REGISTERS; per iteration only the
// 28-cell window ring is read from LDS and the 20-cell patch ring written.
// cur/nxt ping-pong kills per-iter register copies. Valid-after-k = [k,49-k];
// after 9 iters = [9,40] = exactly the output tile. Image-edge replicate
// pads are register fixups on patch-INTERIOR cells (never LDS-read by
// neighbors; verified window ranges), row-fix before col-fix -> corners exact.

#define SROW 52
#define TROW 50
#define OW 32
#define RAD 9
#define NT 64

__device__ __forceinline__ float min3f(float a, float b, float c) { return fminf(fminf(a, b), c); }
__device__ __forceinline__ float max3f(float a, float b, float c) { return fmaxf(fmaxf(a, b), c); }
__device__ __forceinline__ float med3f(float a, float b, float c) { return __builtin_amdgcn_fmed3f(a, b, c); }

__global__ __launch_bounds__(NT, 3) void median_fused_kernel(
    const float* __restrict__ src, float* __restrict__ dst,
    const int* __restrict__ t)
{
    __shared__ float buf[TROW * SROW];

    const int b   = blockIdx.y;
    const int y0  = (blockIdx.x >> 4) * OW;   // 16x16 tiles of 32
    const int x0  = (blockIdx.x & 15) * OW;
    const int tid = threadIdx.x;
    const float* img  = src + (b << 18);
    float*       outb = dst + (b << 18);

    int T = t[b];
    T = min(max(T, 0), 9);

    const int rg = tid >> 3;            // store: 8 row groups
    const int c4 = (tid & 7) << 2;      // store: 8 x float4 per row

    if (T == 0) {                       // straight vector copy, no LDS
        #pragma unroll
        for (int pass = 0; pass < 4; ++pass) {
            int gy = y0 + rg + pass * 8;
            *(float4*)&outb[(gy << 9) + x0 + c4] =
                *(const float4*)&img[(gy << 9) + x0 + c4];
        }
        return;
    }

    // ---- load 50x50 halo tile, clamped (= replicate-padded image) ----
    for (int i = tid; i < TROW * SROW; i += NT) {
        int r = i / SROW, c = i - r * SROW;
        c = min(c, TROW - 1);                        // pad cols 50,51 harmless
        int gy = min(max(y0 - RAD + r, 0), 511);
        int gx = min(max(x0 - RAD + c, 0), 511);
        buf[i] = img[(gy << 9) + gx];
    }

    const bool topE = (y0 == 0), botE = (y0 == 512 - OW);
    const bool lftE = (x0 == 0), rgtE = (x0 == 512 - OW);

    const int pty = tid >> 3;           // 8 row groups x 6
    const int ptx = tid & 7;            // 8 col groups x 6
    const int ub  = 1 + 6 * pty;        // patch rows [ub, ub+5]
    const int vb  = 1 + 6 * ptx;        // patch cols [vb, vb+5]

    // pad roles: image row 0 = tile row 9 (pty=1, i=2; pad row 8 = i=1);
    // image row 511 = tile row 40 (pty=6, i=3; pad row 41 = i=4). Cols sym.
    const bool padTop = topE && (pty == 1);
    const bool padBot = botE && (pty == 6);
    const bool padLft = lftE && (ptx == 1);
    const bool padRgt = rgtE && (ptx == 6);

    auto body = [&](const float (&cur)[36], float (&nxt)[36]) {
        float A[8], Bx[8], C[8];
        {
            const float* p = &buf[(ub - 1) * SROW + (vb - 1)];
            #pragma unroll
            for (int j = 0; j < 8; ++j) A[j] = p[j];
        }
        Bx[0] = buf[ub * SROW + (vb - 1)];
        #pragma unroll
        for (int j = 0; j < 6; ++j) Bx[1 + j] = cur[j];
        Bx[7] = buf[ub * SROW + (vb + 6)];

        #pragma unroll
        for (int i = 0; i < 6; ++i) {
            if (i < 5) {
                C[0] = buf[(ub + 1 + i) * SROW + (vb - 1)];
                #pragma unroll
                for (int j = 0; j < 6; ++j) C[1 + j] = cur[(i + 1) * 6 + j];
                C[7] = buf[(ub + 1 + i) * SROW + (vb + 6)];
            } else {
                const float* q = &buf[(ub + 6) * SROW + (vb - 1)];
                #pragma unroll
                for (int j = 0; j < 8; ++j) C[j] = q[j];
            }
            float lo[8], mi[8], hi[8];
            #pragma unroll
            for (int j = 0; j < 8; ++j) {
                lo[j] = min3f(A[j], Bx[j], C[j]);
                mi[j] = med3f(A[j], Bx[j], C[j]);
                hi[j] = max3f(A[j], Bx[j], C[j]);
            }
            #pragma unroll
            for (int j = 0; j < 6; ++j)
                nxt[i * 6 + j] = med3f(max3f(lo[j], lo[j+1], lo[j+2]),
                                       med3f(mi[j], mi[j+1], mi[j+2]),
                                       min3f(hi[j], hi[j+1], hi[j+2]));
            #pragma unroll
            for (int j = 0; j < 8; ++j) { A[j] = Bx[j]; Bx[j] = C[j]; }
        }
        // register pad fixups (row fix first, then col -> corners exact)
        if (padTop) {
            #pragma unroll
            for (int j = 0; j < 6; ++j) nxt[6 + j]  = nxt[12 + j];
        }
        if (padBot) {
            #pragma unroll
            for (int j = 0; j < 6; ++j) nxt[24 + j] = nxt[18 + j];
        }
        if (padLft) {
            #pragma unroll
            for (int i = 0; i < 6; ++i) nxt[i * 6 + 1] = nxt[i * 6 + 2];
        }
        if (padRgt) {
            #pragma unroll
            for (int i = 0; i < 6; ++i) nxt[i * 6 + 4] = nxt[i * 6 + 3];
        }
    };

    auto writeback = [&](const float (&ns)[36], bool full) {
        if (full) {
            #pragma unroll
            for (int i = 0; i < 6; ++i)
                #pragma unroll
                for (int j = 0; j < 6; ++j)
                    buf[(ub + i) * SROW + vb + j] = ns[i * 6 + j];
        } else {
            #pragma unroll
            for (int j = 0; j < 6; ++j) buf[ub * SROW + vb + j]       = ns[j];
            #pragma unroll
            for (int j = 0; j < 6; ++j) buf[(ub + 5) * SROW + vb + j] = ns[30 + j];
            #pragma unroll
            for (int i = 1; i < 5; ++i) {
                buf[(ub + i) * SROW + vb]     = ns[i * 6];
                buf[(ub + i) * SROW + vb + 5] = ns[i * 6 + 5];
            }
        }
    };

    __syncthreads();                    // fence: tile load visible (no s_barrier)

    float s0[36], s1[36];
    #pragma unroll
    for (int i = 0; i < 6; ++i)
        #pragma unroll
        for (int j = 0; j < 6; ++j)
            s0[i * 6 + j] = buf[(ub + i) * SROW + vb + j];

    for (int k = 0; k < T; ++k) {
        const bool last = (k == T - 1);
        if (k & 1) {
            body(s1, s0);
            __syncthreads();            // ring reads of state k done
            writeback(s0, last);
        } else {
            body(s0, s1);
            __syncthreads();
            writeback(s1, last);
        }
        __syncthreads();                // new ring visible
    }

    // ---- store 32x32 output tile, float4 global stores ----
    #pragma unroll
    for (int pass = 0; pass < 4; ++pass) {
        int row = rg + pass * 8;
        const float* s = &buf[(row + RAD) * SROW + RAD + c4];
        float4 v = { s[0], s[1], s[2], s[3] };
        *(float4*)&outb[((y0 + row) << 9) + x0 + c4] = v;
    }
}

extern "C" void kernel_launch(void* const* d_in, const int* in_sizes, int n_in,
                              void* d_out, int out_size, void* d_ws, size_t ws_size,
                              hipStream_t stream) {
    const float* x   = (const float*)d_in[0];
    const int*   t   = (const int*)d_in[1];
    float*       out = (float*)d_out;

    dim3 block(NT);
    dim3 grid(256, 32);   // 16x16 tiles x 32 batches, 1 wave per block
    median_fused_kernel<<<grid, block, 0, stream>>>(x, out, t);
}

// Round 9
// 114.519 us; speedup vs baseline: 1.1518x; 1.1518x over previous
//
#include <hip/hip_runtime.h>

// Fused iterated 3x3 median blur (edge-replicate), up to 9 iterations.
// 64x64 output tile + 9 halo = 82x82 LDS (26.9 KB -> 6 blocks/CU, 24 waves).
// Each thread owns a contiguous 5x5 patch of compute region [1,80]^2 kept in
// registers. IN-PLACE row sweep: freshly computed row i overwrites stage[i]
// (row i is last consumed when loading window row i+1 at the previous step),
// eliminating the ns[25] double buffer and per-iter copies -> VGPR <= 85 so
// occupancy reaches the LDS cap (6 blocks x 4 waves). Per iteration: 24 ring
// reads from LDS, 16 ring writes (25 on final iter). Image-edge replicate
// pads are register fixups (row fix then col fix -> corners exact); ring
// writes then carry pad values to LDS for neighbor reads.

#define TD 82
#define OW 64
#define RAD 9
#define NT 256

__device__ __forceinline__ float min3f(float a, float b, float c) { return fminf(fminf(a, b), c); }
__device__ __forceinline__ float max3f(float a, float b, float c) { return fmaxf(fmaxf(a, b), c); }
__device__ __forceinline__ float med3f(float a, float b, float c) { return __builtin_amdgcn_fmed3f(a, b, c); }

__global__ __launch_bounds__(NT, 6) void median_fused_kernel(
    const float* __restrict__ src, float* __restrict__ dst,
    const int* __restrict__ t)
{
    __shared__ float buf[TD * TD];

    const int b   = blockIdx.y;
    const int y0  = (blockIdx.x >> 3) * OW;   // 8x8 tiles of 64
    const int x0  = (blockIdx.x & 7) * OW;
    const int tid = threadIdx.x;
    const float* img  = src + (b << 18);
    float*       outb = dst + (b << 18);

    int T = t[b];
    T = min(max(T, 0), 9);

    const int sr = tid >> 4;            // store: 16 row groups x 4
    const int sc = (tid & 15) << 2;     // store: 16 x float4

    if (T == 0) {                       // straight vector copy, no LDS
        #pragma unroll
        for (int rr = 0; rr < 4; ++rr) {
            int gy = y0 + sr + rr * 16;
            *(float4*)&outb[(gy << 9) + x0 + sc] =
                *(const float4*)&img[(gy << 9) + x0 + sc];
        }
        return;
    }

    // ---- load 82x82 halo tile, clamped (= replicate-padded image) ----
    for (int i = tid; i < TD * TD; i += NT) {
        int r = i / TD, c = i - r * TD;
        int gy = min(max(y0 - RAD + r, 0), 511);
        int gx = min(max(x0 - RAD + c, 0), 511);
        buf[i] = img[(gy << 9) + gx];
    }

    const bool topE = (y0 == 0), botE = (y0 == 512 - OW);
    const bool lftE = (x0 == 0), rgtE = (x0 == 512 - OW);

    const int ptx = tid & 15;           // 16 col groups x 5
    const int pty = tid >> 4;           // 16 row groups x 5
    const int ub  = 1 + 5 * pty;        // patch rows [ub, ub+4]
    const int vb  = 1 + 5 * ptx;        // patch cols [vb, vb+4]

    // pad roles: image row 0 = tile row 9 = pty==1 i=3 (pad row 8 = i=2);
    // image row 511 = tile row 72 = pty==14 i=1 (pad row 73 = i=2). Cols sym.
    const bool padTop = topE && (pty == 1);
    const bool padBot = botE && (pty == 14);
    const bool padLft = lftE && (ptx == 1);
    const bool padRgt = rgtE && (ptx == 14);

    __syncthreads();

    // preload own 5x5 patch (state 0) into registers
    float stage[25];
    #pragma unroll
    for (int i = 0; i < 5; ++i)
        #pragma unroll
        for (int j = 0; j < 5; ++j)
            stage[i * 5 + j] = buf[(ub + i) * TD + vb + j];

    for (int k = 0; k < T; ++k) {
        float A[7], Bx[7], C[7];
        // window row ub-1: all 7 from LDS (neighbor ring)
        {
            const float* p = &buf[(ub - 1) * TD + (vb - 1)];
            #pragma unroll
            for (int j = 0; j < 7; ++j) A[j] = p[j];
        }
        // window row ub: edges from LDS, middle from stage row 0
        Bx[0] = buf[ub * TD + (vb - 1)];
        #pragma unroll
        for (int j = 0; j < 5; ++j) Bx[1 + j] = stage[j];
        Bx[6] = buf[ub * TD + (vb + 5)];

        #pragma unroll
        for (int i = 0; i < 5; ++i) {
            if (i < 4) {                // rows ub+1..ub+4: edges LDS, mid regs
                C[0] = buf[(ub + 1 + i) * TD + (vb - 1)];
                #pragma unroll
                for (int j = 0; j < 5; ++j) C[1 + j] = stage[(i + 1) * 5 + j];
                C[6] = buf[(ub + 1 + i) * TD + (vb + 5)];
            } else {                    // row ub+5: all 7 from LDS
                const float* q = &buf[(ub + 5) * TD + (vb - 1)];
                #pragma unroll
                for (int j = 0; j < 7; ++j) C[j] = q[j];
            }
            float lo[7], mi[7], hi[7];
            #pragma unroll
            for (int j = 0; j < 7; ++j) {
                lo[j] = min3f(A[j], Bx[j], C[j]);
                mi[j] = med3f(A[j], Bx[j], C[j]);
                hi[j] = max3f(A[j], Bx[j], C[j]);
            }
            // in-place: stage row i was last consumed loading window row i+1
            #pragma unroll
            for (int j = 0; j < 5; ++j)
                stage[i * 5 + j] = med3f(max3f(lo[j], lo[j+1], lo[j+2]),
                                         med3f(mi[j], mi[j+1], mi[j+2]),
                                         min3f(hi[j], hi[j+1], hi[j+2]));
            #pragma unroll
            for (int j = 0; j < 7; ++j) { A[j] = Bx[j]; Bx[j] = C[j]; }
        }

        // register pad fixups (row fix first, then col -> corners exact)
        if (padTop) {                   // pad row 8 (i=2) <- new row 9 (i=3)
            #pragma unroll
            for (int j = 0; j < 5; ++j) stage[10 + j] = stage[15 + j];
        }
        if (padBot) {                   // pad row 73 (i=2) <- new row 72 (i=1)
            #pragma unroll
            for (int j = 0; j < 5; ++j) stage[10 + j] = stage[5 + j];
        }
        if (padLft) {                   // pad col 8 (j=2) <- new col 9 (j=3)
            #pragma unroll
            for (int i = 0; i < 5; ++i) stage[i * 5 + 2] = stage[i * 5 + 3];
        }
        if (padRgt) {                   // pad col 73 (j=2) <- new col 72 (j=1)
            #pragma unroll
            for (int i = 0; i < 5; ++i) stage[i * 5 + 2] = stage[i * 5 + 1];
        }

        __syncthreads();                // all ring reads of state k done

        if (k == T - 1) {               // final: write all 25 for store phase
            #pragma unroll
            for (int i = 0; i < 5; ++i)
                #pragma unroll
                for (int j = 0; j < 5; ++j)
                    buf[(ub + i) * TD + vb + j] = stage[i * 5 + j];
        } else {                        // write the 16-cell patch ring only
            #pragma unroll
            for (int j = 0; j < 5; ++j) buf[ub * TD + vb + j]       = stage[j];
            #pragma unroll
            for (int j = 0; j < 5; ++j) buf[(ub + 4) * TD + vb + j] = stage[20 + j];
            #pragma unroll
            for (int i = 1; i < 4; ++i) {
                buf[(ub + i) * TD + vb]     = stage[i * 5];
                buf[(ub + i) * TD + vb + 4] = stage[i * 5 + 4];
            }
        }

        __syncthreads();                // new ring visible
    }

    // ---- store 64x64 output tile, float4 global stores ----
    #pragma unroll
    for (int rr = 0; rr < 4; ++rr) {
        int row = sr + rr * 16;
        const float* s = &buf[(row + RAD) * TD + RAD + sc];
        float4 v = { s[0], s[1], s[2], s[3] };
        *(float4*)&outb[((y0 + row) << 9) + x0 + sc] = v;
    }
}

extern "C" void kernel_launch(void* const* d_in, const int* in_sizes, int n_in,
                              void* d_out, int out_size, void* d_ws, size_t ws_size,
                              hipStream_t stream) {
    const float* x   = (const float*)d_in[0];
    const int*   t   = (const int*)d_in[1];
    float*       out = (float*)d_out;

    dim3 block(NT);
    dim3 grid(64, 32);   // 8x8 full tiles x 32 batches
    median_fused_kernel<<<grid, block, 0, stream>>>(x, out, t);
}

// Round 10
// 108.872 us; speedup vs baseline: 1.2115x; 1.0519x over previous
//
#include <hip/hip_runtime.h>

// Fused iterated 3x3 median blur (edge-replicate), up to 9 iterations.
// 64x64 output tile + 9 halo = 82x82 LDS (26.9 KB -> 6 blocks/CU).
// Block = 128 threads (2 waves); each thread owns a TALL 10x5 patch of
// compute region [1,80]^2 (6400 = 128*50) kept in registers. Merging two
// 5x5 patches vertically removes the shared boundary exchange: 34 ring
// reads + 26 ring writes per 50 cells (vs 48+32), and each wave carries 2x
// independent work (ILP replaces TLP; 6 blocks x 2 waves = 12 waves/CU).
// IN-PLACE row sweep: stage row i is last read at step i-1, so step i may
// overwrite it. Valid-after-k = [k,81-k]; after 9 iters = [9,72] = output.
// Image-edge replicate pads are register fixups (row fix then col fix).

#define TD 82
#define OW 64
#define RAD 9
#define NT 128

__device__ __forceinline__ float min3f(float a, float b, float c) { return fminf(fminf(a, b), c); }
__device__ __forceinline__ float max3f(float a, float b, float c) { return fmaxf(fmaxf(a, b), c); }
__device__ __forceinline__ float med3f(float a, float b, float c) { return __builtin_amdgcn_fmed3f(a, b, c); }

__global__ __launch_bounds__(NT) void median_fused_kernel(
    const float* __restrict__ src, float* __restrict__ dst,
    const int* __restrict__ t)
{
    __shared__ float buf[TD * TD];

    const int b   = blockIdx.y;
    const int y0  = (blockIdx.x >> 3) * OW;   // 8x8 tiles of 64
    const int x0  = (blockIdx.x & 7) * OW;
    const int tid = threadIdx.x;
    const float* img  = src + (b << 18);
    float*       outb = dst + (b << 18);

    int T = t[b];
    T = min(max(T, 0), 9);

    const int sr = tid >> 4;            // store: 8 row groups x 8 passes
    const int sc = (tid & 15) << 2;     // store: 16 x float4

    if (T == 0) {                       // straight vector copy, no LDS
        #pragma unroll
        for (int pass = 0; pass < 8; ++pass) {
            int gy = y0 + sr + pass * 8;
            *(float4*)&outb[(gy << 9) + x0 + sc] =
                *(const float4*)&img[(gy << 9) + x0 + sc];
        }
        return;
    }

    // ---- load 82x82 halo tile, clamped (= replicate-padded image) ----
    for (int i = tid; i < TD * TD; i += NT) {
        int r = i / TD, c = i - r * TD;
        int gy = min(max(y0 - RAD + r, 0), 511);
        int gx = min(max(x0 - RAD + c, 0), 511);
        buf[i] = img[(gy << 9) + gx];
    }

    const bool topE = (y0 == 0), botE = (y0 == 512 - OW);
    const bool lftE = (x0 == 0), rgtE = (x0 == 512 - OW);

    const int ptx = tid & 15;           // 16 col groups x 5
    const int pty = tid >> 4;           // 8 row groups x 10
    const int ub  = 1 + 10 * pty;       // patch rows [ub, ub+9]
    const int vb  = 1 + 5 * ptx;        // patch cols [vb, vb+4]

    // pad roles: image row 0 = tile row 9 -> pty==0, i=8 (pad row 8 = i=7);
    // image row 511 = tile row 72 -> pty==7, i=1 (pad row 73 = i=2).
    // cols: image col 0 = tile col 9 -> ptx==1, j=3 (pad col 8 = j=2);
    // image col 511 = tile col 72 -> ptx==14, j=1 (pad col 73 = j=2).
    const bool padTop = topE && (pty == 0);
    const bool padBot = botE && (pty == 7);
    const bool padLft = lftE && (ptx == 1);
    const bool padRgt = rgtE && (ptx == 14);

    __syncthreads();

    // preload own 10x5 patch (state 0) into registers
    float stage[50];
    #pragma unroll
    for (int i = 0; i < 10; ++i)
        #pragma unroll
        for (int j = 0; j < 5; ++j)
            stage[i * 5 + j] = buf[(ub + i) * TD + vb + j];

    for (int k = 0; k < T; ++k) {
        float A[7], Bx[7], C[7];
        // window row ub-1: all 7 from LDS (neighbor ring)
        {
            const float* p = &buf[(ub - 1) * TD + (vb - 1)];
            #pragma unroll
            for (int j = 0; j < 7; ++j) A[j] = p[j];
        }
        // window row ub: edges from LDS, middle from stage row 0
        Bx[0] = buf[ub * TD + (vb - 1)];
        #pragma unroll
        for (int j = 0; j < 5; ++j) Bx[1 + j] = stage[j];
        Bx[6] = buf[ub * TD + (vb + 5)];

        #pragma unroll
        for (int i = 0; i < 10; ++i) {
            if (i < 9) {                // rows ub+1..ub+9: edges LDS, mid regs
                C[0] = buf[(ub + 1 + i) * TD + (vb - 1)];
                #pragma unroll
                for (int j = 0; j < 5; ++j) C[1 + j] = stage[(i + 1) * 5 + j];
                C[6] = buf[(ub + 1 + i) * TD + (vb + 5)];
            } else {                    // row ub+10: all 7 from LDS
                const float* q = &buf[(ub + 10) * TD + (vb - 1)];
                #pragma unroll
                for (int j = 0; j < 7; ++j) C[j] = q[j];
            }
            float lo[7], mi[7], hi[7];
            #pragma unroll
            for (int j = 0; j < 7; ++j) {
                lo[j] = min3f(A[j], Bx[j], C[j]);
                mi[j] = med3f(A[j], Bx[j], C[j]);
                hi[j] = max3f(A[j], Bx[j], C[j]);
            }
            // in-place: stage row i was last read at step i-1
            #pragma unroll
            for (int j = 0; j < 5; ++j)
                stage[i * 5 + j] = med3f(max3f(lo[j], lo[j+1], lo[j+2]),
                                         med3f(mi[j], mi[j+1], mi[j+2]),
                                         min3f(hi[j], hi[j+1], hi[j+2]));
            #pragma unroll
            for (int j = 0; j < 7; ++j) { A[j] = Bx[j]; Bx[j] = C[j]; }
        }

        // register pad fixups (row fix first, then col -> corners exact)
        if (padTop) {                   // pad row 8 (i=7) <- new row 9 (i=8)
            #pragma unroll
            for (int j = 0; j < 5; ++j) stage[35 + j] = stage[40 + j];
        }
        if (padBot) {                   // pad row 73 (i=2) <- new row 72 (i=1)
            #pragma unroll
            for (int j = 0; j < 5; ++j) stage[10 + j] = stage[5 + j];
        }
        if (padLft) {                   // pad col 8 (j=2) <- new col 9 (j=3)
            #pragma unroll
            for (int i = 0; i < 10; ++i) stage[i * 5 + 2] = stage[i * 5 + 3];
        }
        if (padRgt) {                   // pad col 73 (j=2) <- new col 72 (j=1)
            #pragma unroll
            for (int i = 0; i < 10; ++i) stage[i * 5 + 2] = stage[i * 5 + 1];
        }

        __syncthreads();                // all ring reads of state k done

        if (k == T - 1) {               // final: write all 50 for store phase
            #pragma unroll
            for (int i = 0; i < 10; ++i)
                #pragma unroll
                for (int j = 0; j < 5; ++j)
                    buf[(ub + i) * TD + vb + j] = stage[i * 5 + j];
        } else {                        // write the 26-cell patch ring only
            #pragma unroll
            for (int j = 0; j < 5; ++j) buf[ub * TD + vb + j]       = stage[j];
            #pragma unroll
            for (int j = 0; j < 5; ++j) buf[(ub + 9) * TD + vb + j] = stage[45 + j];
            #pragma unroll
            for (int i = 1; i < 9; ++i) {
                buf[(ub + i) * TD + vb]     = stage[i * 5];
                buf[(ub + i) * TD + vb + 4] = stage[i * 5 + 4];
            }
        }

        __syncthreads();                // new ring visible
    }

    // ---- store 64x64 output tile, float4 global stores ----
    #pragma unroll
    for (int pass = 0; pass < 8; ++pass) {
        int row = sr + pass * 8;
        const float* s = &buf[(row + RAD) * TD + RAD + sc];
        float4 v = { s[0], s[1], s[2], s[3] };
        *(float4*)&outb[((y0 + row) << 9) + x0 + sc] = v;
    }
}

extern "C" void kernel_launch(void* const* d_in, const int* in_sizes, int n_in,
                              void* d_out, int out_size, void* d_ws, size_t ws_size,
                              hipStream_t stream) {
    const float* x   = (const float*)d_in[0];
    const int*   t   = (const int*)d_in[1];
    float*       out = (float*)d_out;

    dim3 block(NT);
    dim3 grid(64, 32);   // 8x8 full tiles x 32 batches
    median_fused_kernel<<<grid, block, 0, stream>>>(x, out, t);
}